// Round 2
// baseline (1173.249 us; speedup 1.0000x reference)
//
#include <hip/hip_runtime.h>

#define N_ 768
#define CS 384
#define CZ 128
#define HH 12
#define PQ_ 4
#define PV_ 8

// ---------------------------------------------------------------------------
// K0: zb[n][m][12] = sqrt(1/3) * (z[n,m,:] @ w_b[h,:] + b_b[h])
// Massively parallel, coalesced z read (the first full-HBM z pass).
// grid = 768 n * 12 m-tiles of 64, block = 256.
// ---------------------------------------------------------------------------
__global__ __launch_bounds__(256, 4) void k_zb(
    const float* __restrict__ z,
    const float* __restrict__ w_b, const float* __restrict__ b_b,
    float* __restrict__ zb)
{
    const int bid = blockIdx.x;
    const int n  = bid / 12;
    const int m0 = (bid % 12) * 64;
    const int tid = threadIdx.x;

    __shared__ float zs[64 * 133];   // 64 rows x 128, stride 133 (odd: no bank conflict)
    __shared__ float zbt[64 * 12];   // staged output tile

    // coalesced load of z[n, m0:m0+64, 0:128]
    const float4* zsrc = (const float4*)(z + ((size_t)n * N_ + m0) * CZ);
    #pragma unroll
    for (int j = 0; j < 8; ++j) {
        int idx = tid + j * 256;            // 2048 float4s
        float4 zv = zsrc[idx];
        int f  = idx << 2;
        int ml = f >> 7;
        int c  = f & 127;
        float* d = &zs[ml * 133 + c];
        d[0] = zv.x; d[1] = zv.y; d[2] = zv.z; d[3] = zv.w;
    }
    __syncthreads();

    // thread = (m-row, head-quarter): 3 heads per thread
    const int ml = tid & 63;
    const int hq = __builtin_amdgcn_readfirstlane(tid >> 6);  // wave-uniform -> s_loads
    const float* w0 = w_b + (hq * 3 + 0) * CZ;
    const float* w1 = w0 + CZ;
    const float* w2 = w1 + CZ;
    const float* zrow = &zs[ml * 133];
    float a0 = 0.f, a1 = 0.f, a2 = 0.f;
    #pragma unroll 8
    for (int c = 0; c < CZ; ++c) {
        float zv = zrow[c];
        a0 += zv * w0[c];
        a1 += zv * w1[c];
        a2 += zv * w2[c];
    }
    const float s3 = 0.5773502691896258f;   // sqrt(1/3)
    zbt[ml * 12 + hq * 3 + 0] = s3 * (a0 + b_b[hq * 3 + 0]);
    zbt[ml * 12 + hq * 3 + 1] = s3 * (a1 + b_b[hq * 3 + 1]);
    zbt[ml * 12 + hq * 3 + 2] = s3 * (a2 + b_b[hq * 3 + 2]);
    __syncthreads();

    // coalesced store: 768 contiguous floats = 192 float4
    float4* dst = (float4*)(zb + ((size_t)n * N_ + m0) * 12);
    if (tid < 192) dst[tid] = ((const float4*)zbt)[tid];
}

// ---------------------------------------------------------------------------
// K1: projections, 2 residues per block (halves weight L2 traffic, 2x ILP).
// raw[0:192]   = q rows
// raw[192:576] = kv rows (h*32 + c; c<16 -> k, else v)
// raw[576:720] = q_pts proj (coord*48 + hp), hp = h*4+p
// raw[720:1152]= kv_pts proj (coord*144 + j), j = h*12+p (p<4 k_pts else v_pts)
// v and v_pts are written TRANSPOSED into vcatT[480][768] (row i, col n).
// ---------------------------------------------------------------------------
__global__ __launch_bounds__(256) void k_proj(
    const float* __restrict__ s,
    const float* __restrict__ rot,
    const float* __restrict__ trans,
    const float* __restrict__ w_q,  const float* __restrict__ b_q,
    const float* __restrict__ w_kv, const float* __restrict__ b_kv,
    const float* __restrict__ w_qp, const float* __restrict__ b_qp,
    const float* __restrict__ w_kvp,const float* __restrict__ b_kvp,
    float* __restrict__ q, float* __restrict__ k,
    float* __restrict__ qp, float* __restrict__ kp,
    float* __restrict__ vcatT)
{
    const int n0  = blockIdx.x * 2;
    const int tid = threadIdx.x;
    __shared__ float s_sh[2][CS];
    __shared__ float raw[2][1152];
    __shared__ float R[2][9], T[2][3];

    for (int i = tid; i < 2 * CS; i += 256) s_sh[i / CS][i % CS] = s[n0 * CS + i];
    if (tid < 18) R[tid / 9][tid % 9] = rot[n0 * 9 + tid];
    if (tid < 6)  T[tid / 3][tid % 3] = trans[n0 * 3 + tid];
    __syncthreads();

    for (int idx = tid; idx < 1152; idx += 256) {
        const float* wrow;
        float bias;
        if (idx < 192)      { wrow = w_q + idx * CS;               bias = b_q[idx]; }
        else if (idx < 576) { int r = idx - 192; wrow = w_kv + r * CS;  bias = b_kv[r]; }
        else if (idx < 720) { int r = idx - 576; wrow = w_qp + r * CS;  bias = b_qp[r]; }
        else                { int r = idx - 720; wrow = w_kvp + r * CS; bias = b_kvp[r]; }
        float acc0 = bias, acc1 = bias;
        const float4* w4 = (const float4*)wrow;
        #pragma unroll 4
        for (int c4 = 0; c4 < CS / 4; ++c4) {
            float4 wv = w4[c4];
            const float* sp0 = &s_sh[0][c4 * 4];
            const float* sp1 = &s_sh[1][c4 * 4];
            acc0 += sp0[0] * wv.x + sp0[1] * wv.y + sp0[2] * wv.z + sp0[3] * wv.w;
            acc1 += sp1[0] * wv.x + sp1[1] * wv.y + sp1[2] * wv.z + sp1[3] * wv.w;
        }
        raw[0][idx] = acc0;
        raw[1][idx] = acc1;
    }
    __syncthreads();

    #pragma unroll
    for (int t = 0; t < 2; ++t) {
        const int n = n0 + t;
        const float* rw = raw[t];
        const float* Rt = R[t];
        const float* Tt = T[t];
        for (int i = tid; i < 192; i += 256) {
            q[n * 192 + i] = rw[i];
            int h = i >> 4, c = i & 15;
            k[n * 192 + i] = rw[192 + h * 32 + c];
            vcatT[(size_t)i * N_ + n] = rw[192 + h * 32 + 16 + c];
        }
        for (int hp = tid; hp < 48; hp += 256) {
            float x = rw[576 + hp], y = rw[576 + 48 + hp], zc = rw[576 + 96 + hp];
            #pragma unroll
            for (int i = 0; i < 3; ++i)
                qp[n * 144 + hp * 3 + i] = Rt[i * 3 + 0] * x + Rt[i * 3 + 1] * y + Rt[i * 3 + 2] * zc + Tt[i];
        }
        for (int j = tid; j < 144; j += 256) {
            float x = rw[720 + j], y = rw[720 + 144 + j], zc = rw[720 + 288 + j];
            float p0 = Rt[0] * x + Rt[1] * y + Rt[2] * zc + Tt[0];
            float p1 = Rt[3] * x + Rt[4] * y + Rt[5] * zc + Tt[1];
            float p2 = Rt[6] * x + Rt[7] * y + Rt[8] * zc + Tt[2];
            int h = j / 12, p = j % 12;
            if (p < PQ_) {
                int o = n * 144 + (h * PQ_ + p) * 3;
                kp[o] = p0; kp[o + 1] = p1; kp[o + 2] = p2;
            } else {
                int base = 192 + (h * PV_ + (p - PQ_)) * 3;
                vcatT[(size_t)(base + 0) * N_ + n] = p0;
                vcatT[(size_t)(base + 1) * N_ + n] = p1;
                vcatT[(size_t)(base + 2) * N_ + n] = p2;
            }
        }
    }
}

// ---------------------------------------------------------------------------
// K2 (fused): per residue n — logits (bias precomputed in k_zb), softmax in
// LDS, o+o_pt streaming contiguous vcatT rows, o_pair = a@z (halves combined
// through oc in global), inv-rot + norms. LDS ~39.5 KB -> 4 blocks/CU.
// ---------------------------------------------------------------------------
__global__ __launch_bounds__(256, 4) void k_fused(
    const float* __restrict__ q, const float* __restrict__ k,
    const float* __restrict__ qp, const float* __restrict__ kp,
    const float* __restrict__ vcatT,
    const float* __restrict__ zb,
    const float* __restrict__ z,
    const float* __restrict__ head_weights,
    const float* __restrict__ mask,
    const float* __restrict__ rot, const float* __restrict__ trans,
    float* __restrict__ ocat)
{
    const int n   = (N_ - 1) - blockIdx.x;
    const int tid = threadIdx.x;

    __shared__ float qv[192], qpt[144];
    __shared__ float hw[HH];
    __shared__ float L[HH * N_];             // 36 KB: logits -> probs
    __shared__ float og[288];
    __shared__ float R[9], T[3];

    for (int i = tid; i < 192; i += 256) qv[i] = q[n * 192 + i];
    for (int i = tid; i < 144; i += 256) qpt[i] = qp[n * 144 + i];
    if (tid < HH) {
        float x = head_weights[tid];
        // softplus(x) * sqrt(1/(3*(PQ*9/2)))
        hw[tid] = 0.13608276348795434f * logf(1.0f + expf(x));
    }
    if (tid < 9) R[tid] = rot[n * 9 + tid];
    if (tid < 3) T[tid] = trans[n * 3 + tid];
    __syncthreads();

    const float mn = mask[n];

    // ---- pass 1: logits for all (h, m); z bias comes precomputed from zb ----
    for (int m = tid; m < N_; m += 256) {
        const float4* zb4 = (const float4*)(zb + (size_t)(n * N_ + m) * 12);
        float4 zq0 = zb4[0], zq1 = zb4[1], zq2 = zb4[2];
        float zbias[12] = { zq0.x, zq0.y, zq0.z, zq0.w,
                            zq1.x, zq1.y, zq1.z, zq1.w,
                            zq2.x, zq2.y, zq2.z, zq2.w };
        float mterm = (mn * mask[m] - 1.0f) * 100000.0f;
        const float4* kr4 = (const float4*)(k  + m * 192);
        const float*  kpr = kp + m * 144;
        #pragma unroll
        for (int h = 0; h < HH; ++h) {
            float acc = 0.f;
            #pragma unroll
            for (int c4 = 0; c4 < 4; ++c4) {
                float4 kv = kr4[h * 4 + c4];
                const float* qq = &qv[h * 16 + c4 * 4];
                acc += qq[0] * kv.x + qq[1] * kv.y + qq[2] * kv.z + qq[3] * kv.w;
            }
            acc *= 0.14433756729740643f;            // sqrt(1/48)
            acc += zbias[h];
            float d2;
            {
                const float4* kq = (const float4*)(kpr + h * 12);
                float4 a = kq[0], b = kq[1], cc = kq[2];
                const float* qp_ = &qpt[h * 12];
                float dx, dy, dz;
                dx = qp_[0] - a.x;  dy = qp_[1] - a.y;  dz = qp_[2] - a.z;
                d2  = dx * dx + dy * dy + dz * dz;
                dx = qp_[3] - a.w;  dy = qp_[4] - b.x;  dz = qp_[5] - b.y;
                d2 += dx * dx + dy * dy + dz * dz;
                dx = qp_[6] - b.z;  dy = qp_[7] - b.w;  dz = qp_[8] - cc.x;
                d2 += dx * dx + dy * dy + dz * dz;
                dx = qp_[9] - cc.y; dy = qp_[10] - cc.z; dz = qp_[11] - cc.w;
                d2 += dx * dx + dy * dy + dz * dz;
            }
            acc -= 0.5f * hw[h] * d2;
            L[h * N_ + m] = acc + mterm;
        }
    }
    __syncthreads();

    // ---- pass 2: softmax per head; wave w handles heads w, w+4, w+8 ----
    {
        const int wv_ = tid >> 6, lane = tid & 63;
        #pragma unroll
        for (int j = 0; j < 3; ++j) {
            const int h = wv_ + 4 * j;
            float vals[12];
            float mx = -1e30f;
            #pragma unroll
            for (int t = 0; t < 12; ++t) {
                vals[t] = L[h * N_ + lane + 64 * t];
                mx = fmaxf(mx, vals[t]);
            }
            #pragma unroll
            for (int off = 32; off; off >>= 1) mx = fmaxf(mx, __shfl_xor(mx, off));
            float sum = 0.f;
            #pragma unroll
            for (int t = 0; t < 12; ++t) { vals[t] = expf(vals[t] - mx); sum += vals[t]; }
            #pragma unroll
            for (int off = 32; off; off >>= 1) sum += __shfl_xor(sum, off);
            float inv = 1.0f / sum;
            #pragma unroll
            for (int t = 0; t < 12; ++t) L[h * N_ + lane + 64 * t] = vals[t] * inv;
        }
    }
    __syncthreads();

    float* oc = ocat + (size_t)n * 2112;

    // ---- o (192) and o_pt (288) in ONE pass: contiguous float4 streams over
    //      vcatT rows; probs read as float4 from LDS ----
    {
        const int i0 = tid;              // 0..255
        const int i1 = tid + 256;        // 256..511 (active < 480)
        const bool act1 = (i1 < 480);
        const int h0 = (i0 < 192) ? (i0 >> 4) : ((i0 - 192) / 24);
        const int h1 = act1 ? ((i1 - 192) / 24) : 0;
        const float4* Lh0 = (const float4*)(L + h0 * N_);
        const float4* Lh1 = (const float4*)(L + h1 * N_);
        const float4* vr0 = (const float4*)(vcatT + (size_t)i0 * N_);
        const float4* vr1 = (const float4*)(vcatT + (size_t)(act1 ? i1 : 0) * N_);
        float a0 = 0.f, a1 = 0.f;
        #pragma unroll 4
        for (int m4 = 0; m4 < N_ / 4; ++m4) {
            float4 l0 = Lh0[m4], x0 = vr0[m4];
            float4 l1 = Lh1[m4], x1 = vr1[m4];
            a0 += l0.x * x0.x + l0.y * x0.y + l0.z * x0.z + l0.w * x0.w;
            a1 += l1.x * x1.x + l1.y * x1.y + l1.z * x1.z + l1.w * x1.w;
        }
        if (i0 < 192) oc[i0] = a0; else og[i0 - 192] = a0;
        if (act1) og[i1 - 192] = a1;
    }

    // ---- o_pair = a @ z; halves combined through oc (global) with a
    //      barrier between store and add (saves 12 KB LDS) ----
    {
        const int c = tid & 127, half = tid >> 7;
        float acc[HH];
        #pragma unroll
        for (int h = 0; h < HH; ++h) acc[h] = 0.f;
        const float* zr = z + (size_t)n * N_ * CZ + c;
        const int m0 = half * 384;
        #pragma unroll 2
        for (int m = m0; m < m0 + 384; ++m) {
            float zz = zr[(size_t)m * CZ];
            #pragma unroll
            for (int h = 0; h < HH; ++h) acc[h] += zz * L[h * N_ + m];
        }
        if (half == 0) {
            #pragma unroll
            for (int h = 0; h < HH; ++h) oc[576 + h * CZ + c] = acc[h];
        }
        __syncthreads();   // orders half0 oc stores AND og writes above
        if (half == 1) {
            #pragma unroll
            for (int h = 0; h < HH; ++h) oc[576 + h * CZ + c] += acc[h];
        }
    }

    // ---- inverse rotation + norms (og is barrier-ordered above) ----
    for (int hp = tid; hp < 96; hp += 256) {
        float gx = og[hp * 3 + 0] - T[0];
        float gy = og[hp * 3 + 1] - T[1];
        float gz = og[hp * 3 + 2] - T[2];
        float lx = R[0] * gx + R[3] * gy + R[6] * gz;
        float ly = R[1] * gx + R[4] * gy + R[7] * gz;
        float lz = R[2] * gx + R[5] * gy + R[8] * gz;
        oc[192 + hp] = lx;
        oc[288 + hp] = ly;
        oc[384 + hp] = lz;
        oc[480 + hp] = sqrtf(lx * lx + ly * ly + lz * lz + 1e-8f);
    }
}

// ---------------------------------------------------------------------------
// K3: out[n][j] = o_cat[n,:] . w_out[j,:] + b_out[j]
// Block = (8-residue octet, 96-column quarter): w_out L2 traffic /4 vs
// 2-residue version, grid stays 384, 2 FMA chains per thread.
// ---------------------------------------------------------------------------
__global__ __launch_bounds__(384, 2) void k_final(
    const float* __restrict__ ocat,
    const float* __restrict__ w_out,
    const float* __restrict__ b_out,
    float* __restrict__ out)
{
    const int nb = blockIdx.x >> 2;       // 0..95: n-octet
    const int jq = blockIdx.x & 3;        // 0..3:  j-quarter
    const int n0 = nb * 8;
    const int tid = threadIdx.x;
    const int j  = jq * 96 + (tid % 96);
    const int g  = tid / 96;              // 0..3: residue-pair within octet

    __shared__ float oc[8][2112];
    for (int i = tid; i < 8 * 2112; i += 384)
        oc[i / 2112][i % 2112] = ocat[(size_t)n0 * 2112 + i];
    __syncthreads();

    float acc0 = b_out[j], acc1 = acc0;
    const float4* w4 = (const float4*)(w_out + (size_t)j * 2112);
    const float* r0 = oc[g * 2];
    const float* r1 = oc[g * 2 + 1];
    #pragma unroll 4
    for (int c4 = 0; c4 < 2112 / 4; ++c4) {
        float4 wv = w4[c4];
        const float* s0 = &r0[c4 * 4];
        const float* s1 = &r1[c4 * 4];
        acc0 += s0[0] * wv.x + s0[1] * wv.y + s0[2] * wv.z + s0[3] * wv.w;
        acc1 += s1[0] * wv.x + s1[1] * wv.y + s1[2] * wv.z + s1[3] * wv.w;
    }
    out[(n0 + 2 * g) * 384 + j]     = acc0;
    out[(n0 + 2 * g + 1) * 384 + j] = acc1;
}

extern "C" void kernel_launch(void* const* d_in, const int* in_sizes, int n_in,
                              void* d_out, int out_size, void* d_ws, size_t ws_size,
                              hipStream_t stream)
{
    const float* s     = (const float*)d_in[0];
    const float* z     = (const float*)d_in[1];
    const float* rot   = (const float*)d_in[2];
    const float* trans = (const float*)d_in[3];
    const float* mask  = (const float*)d_in[4];
    const float* w_q   = (const float*)d_in[5];
    const float* b_q   = (const float*)d_in[6];
    const float* w_kv  = (const float*)d_in[7];
    const float* b_kv  = (const float*)d_in[8];
    const float* w_qp  = (const float*)d_in[9];
    const float* b_qp  = (const float*)d_in[10];
    const float* w_kvp = (const float*)d_in[11];
    const float* b_kvp = (const float*)d_in[12];
    const float* w_b   = (const float*)d_in[13];
    const float* b_b   = (const float*)d_in[14];
    const float* hwts  = (const float*)d_in[15];
    const float* w_out = (const float*)d_in[16];
    const float* b_out = (const float*)d_in[17];

    float* ws    = (float*)d_ws;
    float* q     = ws;                    // 768*192      =   147456
    float* k     = q     + 147456;        // 768*192      =   147456
    float* qp    = k     + 147456;        // 768*144      =   110592
    float* kp    = qp    + 110592;        // 768*144      =   110592
    float* vcatT = kp    + 110592;        // 480*768      =   368640 (transposed)
    float* zb    = vcatT + 368640;        // 768*768*12   =  7077888
    float* ocat  = zb    + 7077888;       // 768*2112     =  1622016
    // total: 9,584,640 floats = 38.3 MB

    k_proj<<<N_ / 2, 256, 0, stream>>>(s, rot, trans, w_q, b_q, w_kv, b_kv,
                                       w_qp, b_qp, w_kvp, b_kvp, q, k, qp, kp, vcatT);
    k_zb<<<N_ * 12, 256, 0, stream>>>(z, w_b, b_b, zb);
    k_fused<<<N_, 256, 0, stream>>>(q, k, qp, kp, vcatT, zb, z,
                                    hwts, mask, rot, trans, ocat);
    k_final<<<N_ / 2, 384, 0, stream>>>(ocat, w_out, b_out, (float*)d_out);
}

// Round 3
// 891.500 us; speedup vs baseline: 1.3160x; 1.3160x over previous
//
#include <hip/hip_runtime.h>

#define N_ 768
#define CS 384
#define CZ 128
#define HH 12
#define PQ_ 4
#define PV_ 8

// ---------------------------------------------------------------------------
// K0: zbT[n][h][m] = sqrt(1/3) * (z[n,m,:] @ w_b[h,:] + b_b[h])
// Transposed output so k_fused phase-1 reads are lane-coalesced over m.
// grid = 768 n * 12 m-tiles of 64, block = 256.
// ---------------------------------------------------------------------------
__global__ __launch_bounds__(256, 4) void k_zb(
    const float* __restrict__ z,
    const float* __restrict__ w_b, const float* __restrict__ b_b,
    float* __restrict__ zbT)
{
    const int bid = blockIdx.x;
    const int n  = bid / 12;
    const int m0 = (bid % 12) * 64;
    const int tid = threadIdx.x;

    __shared__ float zs[64 * 133];   // 64 rows x 128, stride 133 (no bank conflict)
    __shared__ float zbt[64 * 13];   // staged output tile, padded stride 13

    // coalesced load of z[n, m0:m0+64, 0:128]
    const float4* zsrc = (const float4*)(z + ((size_t)n * N_ + m0) * CZ);
    #pragma unroll
    for (int j = 0; j < 8; ++j) {
        int idx = tid + j * 256;            // 2048 float4s
        float4 zv = zsrc[idx];
        int f  = idx << 2;
        int ml = f >> 7;
        int c  = f & 127;
        float* d = &zs[ml * 133 + c];
        d[0] = zv.x; d[1] = zv.y; d[2] = zv.z; d[3] = zv.w;
    }
    __syncthreads();

    // thread = (m-row, head-quarter): 3 heads per thread
    const int ml = tid & 63;
    const int hq = __builtin_amdgcn_readfirstlane(tid >> 6);  // wave-uniform -> s_loads
    const float* w0 = w_b + (hq * 3 + 0) * CZ;
    const float* w1 = w0 + CZ;
    const float* w2 = w1 + CZ;
    const float* zrow = &zs[ml * 133];
    float a0 = 0.f, a1 = 0.f, a2 = 0.f;
    #pragma unroll 8
    for (int c = 0; c < CZ; ++c) {
        float zv = zrow[c];
        a0 += zv * w0[c];
        a1 += zv * w1[c];
        a2 += zv * w2[c];
    }
    const float s3 = 0.5773502691896258f;   // sqrt(1/3)
    zbt[ml * 13 + hq * 3 + 0] = s3 * (a0 + b_b[hq * 3 + 0]);
    zbt[ml * 13 + hq * 3 + 1] = s3 * (a1 + b_b[hq * 3 + 1]);
    zbt[ml * 13 + hq * 3 + 2] = s3 * (a2 + b_b[hq * 3 + 2]);
    __syncthreads();

    // transposed coalesced store: for each h, 64 contiguous floats at m0
    for (int idx = tid; idx < 768; idx += 256) {
        int h = idx >> 6, mm = idx & 63;
        zbT[(size_t)n * (HH * N_) + h * N_ + m0 + mm] = zbt[mm * 13 + h];
    }
}

// ---------------------------------------------------------------------------
// K1: projections, 2 residues per block.
// Writes: q[n][192] (row), qp[n][144] (row),
//         kT[192][768], kpT[144][768]  (transposed, float2 over the n-pair),
//         vcat[n][480] = [v(192) | vp(288)]  (row; consumers read columns,
//         which is lane-coalesced).
// kpT channel index = h*12 + p*3 + d (matches qp row layout).
// ---------------------------------------------------------------------------
__global__ __launch_bounds__(256) void k_proj(
    const float* __restrict__ s,
    const float* __restrict__ rot,
    const float* __restrict__ trans,
    const float* __restrict__ w_q,  const float* __restrict__ b_q,
    const float* __restrict__ w_kv, const float* __restrict__ b_kv,
    const float* __restrict__ w_qp, const float* __restrict__ b_qp,
    const float* __restrict__ w_kvp,const float* __restrict__ b_kvp,
    float* __restrict__ q, float* __restrict__ kT,
    float* __restrict__ qp, float* __restrict__ kpT,
    float* __restrict__ vcat)
{
    const int n0  = blockIdx.x * 2;
    const int tid = threadIdx.x;
    __shared__ float s_sh[2][CS];
    __shared__ float raw[2][1152];
    __shared__ float R[2][9], T[2][3];

    for (int i = tid; i < 2 * CS; i += 256) s_sh[i / CS][i % CS] = s[n0 * CS + i];
    if (tid < 18) R[tid / 9][tid % 9] = rot[n0 * 9 + tid];
    if (tid < 6)  T[tid / 3][tid % 3] = trans[n0 * 3 + tid];
    __syncthreads();

    for (int idx = tid; idx < 1152; idx += 256) {
        const float* wrow;
        float bias;
        if (idx < 192)      { wrow = w_q + idx * CS;               bias = b_q[idx]; }
        else if (idx < 576) { int r = idx - 192; wrow = w_kv + r * CS;  bias = b_kv[r]; }
        else if (idx < 720) { int r = idx - 576; wrow = w_qp + r * CS;  bias = b_qp[r]; }
        else                { int r = idx - 720; wrow = w_kvp + r * CS; bias = b_kvp[r]; }
        float acc0 = bias, acc1 = bias;
        const float4* w4 = (const float4*)wrow;
        #pragma unroll 4
        for (int c4 = 0; c4 < CS / 4; ++c4) {
            float4 wv = w4[c4];
            const float* sp0 = &s_sh[0][c4 * 4];
            const float* sp1 = &s_sh[1][c4 * 4];
            acc0 += sp0[0] * wv.x + sp0[1] * wv.y + sp0[2] * wv.z + sp0[3] * wv.w;
            acc1 += sp1[0] * wv.x + sp1[1] * wv.y + sp1[2] * wv.z + sp1[3] * wv.w;
        }
        raw[0][idx] = acc0;
        raw[1][idx] = acc1;
    }
    __syncthreads();

    // q / kT / v
    for (int i = tid; i < 192; i += 256) {
        q[n0 * 192 + i]       = raw[0][i];
        q[(n0 + 1) * 192 + i] = raw[1][i];
        int h = i >> 4, c = i & 15;
        float2 kv2 = make_float2(raw[0][192 + h * 32 + c], raw[1][192 + h * 32 + c]);
        *(float2*)&kT[(size_t)i * N_ + n0] = kv2;
        vcat[n0 * 480 + i]       = raw[0][192 + h * 32 + 16 + c];
        vcat[(n0 + 1) * 480 + i] = raw[1][192 + h * 32 + 16 + c];
    }
    // q_pts (row layout per n)
    #pragma unroll
    for (int t = 0; t < 2; ++t) {
        const float* rw = raw[t];
        const float* Rt = R[t];
        const float* Tt = T[t];
        const int n = n0 + t;
        for (int hp = tid; hp < 48; hp += 256) {
            float x = rw[576 + hp], y = rw[576 + 48 + hp], zc = rw[576 + 96 + hp];
            #pragma unroll
            for (int i = 0; i < 3; ++i)
                qp[n * 144 + hp * 3 + i] = Rt[i * 3 + 0] * x + Rt[i * 3 + 1] * y + Rt[i * 3 + 2] * zc + Tt[i];
        }
    }
    // k_pts (transposed float2) / v_pts (row into vcat)
    for (int j = tid; j < 144; j += 256) {
        float p[2][3];
        #pragma unroll
        for (int t = 0; t < 2; ++t) {
            float x = raw[t][720 + j], y = raw[t][720 + 144 + j], zc = raw[t][720 + 288 + j];
            const float* Rt = R[t];
            const float* Tt = T[t];
            p[t][0] = Rt[0] * x + Rt[1] * y + Rt[2] * zc + Tt[0];
            p[t][1] = Rt[3] * x + Rt[4] * y + Rt[5] * zc + Tt[1];
            p[t][2] = Rt[6] * x + Rt[7] * y + Rt[8] * zc + Tt[2];
        }
        int h = j / 12, pp = j % 12;
        if (pp < PQ_) {
            int ch = h * 12 + pp * 3;          // + d
            #pragma unroll
            for (int d = 0; d < 3; ++d)
                *(float2*)&kpT[(size_t)(ch + d) * N_ + n0] = make_float2(p[0][d], p[1][d]);
        } else {
            int base = 192 + (h * PV_ + (pp - PQ_)) * 3;
            #pragma unroll
            for (int d = 0; d < 3; ++d) {
                vcat[n0 * 480 + base + d]       = p[0][d];
                vcat[(n0 + 1) * 480 + base + d] = p[1][d];
            }
        }
    }
}

// ---------------------------------------------------------------------------
// K2 (fused): per residue n.
// phase1: logits via TRANSPOSED kT/kpT/zbT — thread = 4 consecutive m
//         (float4), every global load lane-coalesced.
// phase2: softmax (unchanged).
// phase3: o + o_pt over vcat columns (lane-coalesced, as round 1).
// phase4: o_pair with float4-of-c x 8 m-groups, shfl fold + LDS tree
//         reduction staged in L's space (L dead), single coalesced store.
// LDS ~38.6 KB -> 4 blocks/CU.
// ---------------------------------------------------------------------------
__global__ __launch_bounds__(256, 4) void k_fused(
    const float* __restrict__ q, const float* __restrict__ kT,
    const float* __restrict__ qp, const float* __restrict__ kpT,
    const float* __restrict__ vcat,
    const float* __restrict__ zbT,
    const float* __restrict__ z,
    const float* __restrict__ head_weights,
    const float* __restrict__ mask,
    const float* __restrict__ rot, const float* __restrict__ trans,
    float* __restrict__ ocat)
{
    const int n   = (N_ - 1) - blockIdx.x;
    const int tid = threadIdx.x;

    __shared__ float qv[192], qpt[144];
    __shared__ float hw[HH];
    __shared__ float L[HH * N_];             // 36 KB: logits -> probs -> (reuse: o_pair partials)
    __shared__ float og[288];
    __shared__ float R[9], T[3];

    for (int i = tid; i < 192; i += 256) qv[i] = q[n * 192 + i];
    for (int i = tid; i < 144; i += 256) qpt[i] = qp[n * 144 + i];
    if (tid < HH) {
        float x = head_weights[tid];
        hw[tid] = 0.13608276348795434f * logf(1.0f + expf(x));  // softplus * sqrt(1/(3*18))
    }
    if (tid < 9) R[tid] = rot[n * 9 + tid];
    if (tid < 3) T[tid] = trans[n * 3 + tid];
    __syncthreads();

    const float mn = mask[n];

    // ---- pass 1: logits; thread = 4 consecutive m, transposed operands ----
    if (tid < 192) {
        const int m0 = tid * 4;
        float4 mk = *(const float4*)(mask + m0);
        float mt0 = (mn * mk.x - 1.0f) * 100000.0f;
        float mt1 = (mn * mk.y - 1.0f) * 100000.0f;
        float mt2 = (mn * mk.z - 1.0f) * 100000.0f;
        float mt3 = (mn * mk.w - 1.0f) * 100000.0f;
        const float* zbn = zbT + (size_t)n * (HH * N_);
        #pragma unroll
        for (int h = 0; h < HH; ++h) {
            float ax = 0.f, ay = 0.f, az = 0.f, aw = 0.f;
            #pragma unroll
            for (int c = 0; c < 16; ++c) {
                float qc = qv[h * 16 + c];
                float4 kx = *(const float4*)&kT[(size_t)(h * 16 + c) * N_ + m0];
                ax += qc * kx.x; ay += qc * kx.y; az += qc * kx.z; aw += qc * kx.w;
            }
            const float s48 = 0.14433756729740643f;   // sqrt(1/48)
            ax *= s48; ay *= s48; az *= s48; aw *= s48;
            float4 zb4 = *(const float4*)&zbn[h * N_ + m0];
            ax += zb4.x; ay += zb4.y; az += zb4.z; aw += zb4.w;
            float dx = 0.f, dy = 0.f, dz = 0.f, dw = 0.f;
            #pragma unroll
            for (int pd = 0; pd < 12; ++pd) {
                float qd = qpt[h * 12 + pd];
                float4 kd = *(const float4*)&kpT[(size_t)(h * 12 + pd) * N_ + m0];
                float ex = qd - kd.x, ey = qd - kd.y, ez = qd - kd.z, ew = qd - kd.w;
                dx += ex * ex; dy += ey * ey; dz += ez * ez; dw += ew * ew;
            }
            float hwh = 0.5f * hw[h];
            float4 out;
            out.x = ax - hwh * dx + mt0;
            out.y = ay - hwh * dy + mt1;
            out.z = az - hwh * dz + mt2;
            out.w = aw - hwh * dw + mt3;
            *(float4*)&L[h * N_ + m0] = out;
        }
    }
    __syncthreads();

    // ---- pass 2: softmax per head; wave w handles heads w, w+4, w+8 ----
    {
        const int wv_ = tid >> 6, lane = tid & 63;
        #pragma unroll
        for (int j = 0; j < 3; ++j) {
            const int h = wv_ + 4 * j;
            float vals[12];
            float mx = -1e30f;
            #pragma unroll
            for (int t = 0; t < 12; ++t) {
                vals[t] = L[h * N_ + lane + 64 * t];
                mx = fmaxf(mx, vals[t]);
            }
            #pragma unroll
            for (int off = 32; off; off >>= 1) mx = fmaxf(mx, __shfl_xor(mx, off));
            float sum = 0.f;
            #pragma unroll
            for (int t = 0; t < 12; ++t) { vals[t] = expf(vals[t] - mx); sum += vals[t]; }
            #pragma unroll
            for (int off = 32; off; off >>= 1) sum += __shfl_xor(sum, off);
            float inv = 1.0f / sum;
            #pragma unroll
            for (int t = 0; t < 12; ++t) L[h * N_ + lane + 64 * t] = vals[t] * inv;
        }
    }
    __syncthreads();

    float* oc = ocat + (size_t)n * 2112;

    // ---- pass 3: o (192) + o_pt (288); vcat column reads, lane-coalesced ----
    {
        const int i0 = tid;              // 0..255
        const int i1 = tid + 256;        // 256..511 (active < 480)
        const bool act1 = (i1 < 480);
        const int h0 = (i0 < 192) ? (i0 >> 4) : ((i0 - 192) / 24);
        const int h1 = act1 ? ((i1 - 192) / 24) : 0;
        const float* Lh0 = L + h0 * N_;
        const float* Lh1 = L + h1 * N_;
        const float* vc0 = vcat + i0;
        const float* vc1 = vcat + (act1 ? i1 : 0);
        float a0 = 0.f, a1 = 0.f;
        #pragma unroll 8
        for (int m = 0; m < N_; ++m) {
            float x0 = vc0[(size_t)m * 480];
            float x1 = vc1[(size_t)m * 480];
            a0 += Lh0[m] * x0;
            a1 += Lh1[m] * x1;
        }
        if (i0 < 192) oc[i0] = a0; else og[i0 - 192] = a0;
        if (act1) og[i1 - 192] = a1;
    }

    // ---- pass 4: o_pair = a @ z; thread = (c-quad, m-group of 96) ----
    {
        const int c4 = tid & 31;         // float4 column group
        const int g  = tid >> 5;         // 0..7 m-group
        const float4* zr = (const float4*)(z + (size_t)n * N_ * CZ) + c4;
        float4 acc[HH];
        #pragma unroll
        for (int h = 0; h < HH; ++h) { acc[h].x = acc[h].y = acc[h].z = acc[h].w = 0.f; }
        const int ms = g * 96;
        #pragma unroll 4
        for (int m = ms; m < ms + 96; ++m) {
            float4 zz = zr[(size_t)m * 32];
            #pragma unroll
            for (int h = 0; h < HH; ++h) {
                float lh = L[h * N_ + m];
                acc[h].x += lh * zz.x; acc[h].y += lh * zz.y;
                acc[h].z += lh * zz.z; acc[h].w += lh * zz.w;
            }
        }
        // fold g-pairs: lanes l and l+32 share c4, differ in g
        #pragma unroll
        for (int h = 0; h < HH; ++h) {
            acc[h].x += __shfl_xor(acc[h].x, 32);
            acc[h].y += __shfl_xor(acc[h].y, 32);
            acc[h].z += __shfl_xor(acc[h].z, 32);
            acc[h].w += __shfl_xor(acc[h].w, 32);
        }
        __syncthreads();                 // all L reads (pass 3+4) complete
        float4* part4 = (float4*)L;      // reuse L's LDS: 4 x 12 x 32 float4 = 24 KB
        if ((tid & 63) < 32) {
            const int w = tid >> 6;      // wave id 0..3 (holds g-pair 2w,2w+1)
            #pragma unroll
            for (int h = 0; h < HH; ++h)
                part4[(w * HH + h) * 32 + c4] = acc[h];
        }
        __syncthreads();
        const float* part = (const float*)L;
        for (int idx = tid; idx < HH * CZ; idx += 256) {
            float sum = part[idx] + part[1536 + idx] + part[3072 + idx] + part[4608 + idx];
            oc[576 + idx] = sum;
        }
    }

    // ---- inverse rotation + norms (og barrier-ordered above) ----
    for (int hp = tid; hp < 96; hp += 256) {
        float gx = og[hp * 3 + 0] - T[0];
        float gy = og[hp * 3 + 1] - T[1];
        float gz = og[hp * 3 + 2] - T[2];
        float lx = R[0] * gx + R[3] * gy + R[6] * gz;
        float ly = R[1] * gx + R[4] * gy + R[7] * gz;
        float lz = R[2] * gx + R[5] * gy + R[8] * gz;
        oc[192 + hp] = lx;
        oc[288 + hp] = ly;
        oc[384 + hp] = lz;
        oc[480 + hp] = sqrtf(lx * lx + ly * ly + lz * lz + 1e-8f);
    }
}

// ---------------------------------------------------------------------------
// K3: out[n][j] = o_cat[n,:] . w_out[j,:] + b_out[j]
// Block = (8-residue octet, 96-column quarter): w_out traffic 311 MB total.
// ---------------------------------------------------------------------------
__global__ __launch_bounds__(384, 2) void k_final(
    const float* __restrict__ ocat,
    const float* __restrict__ w_out,
    const float* __restrict__ b_out,
    float* __restrict__ out)
{
    const int nb = blockIdx.x >> 2;       // 0..95: n-octet
    const int jq = blockIdx.x & 3;        // 0..3:  j-quarter
    const int n0 = nb * 8;
    const int tid = threadIdx.x;
    const int j  = jq * 96 + (tid % 96);
    const int g  = tid / 96;              // 0..3: residue-pair within octet

    __shared__ float oc[8][2112];
    for (int i = tid; i < 8 * 2112; i += 384)
        oc[i / 2112][i % 2112] = ocat[(size_t)n0 * 2112 + i];
    __syncthreads();

    float acc0 = b_out[j], acc1 = acc0;
    const float4* w4 = (const float4*)(w_out + (size_t)j * 2112);
    const float* r0 = oc[g * 2];
    const float* r1 = oc[g * 2 + 1];
    #pragma unroll 4
    for (int c4 = 0; c4 < 2112 / 4; ++c4) {
        float4 wv = w4[c4];
        const float* s0 = &r0[c4 * 4];
        const float* s1 = &r1[c4 * 4];
        acc0 += s0[0] * wv.x + s0[1] * wv.y + s0[2] * wv.z + s0[3] * wv.w;
        acc1 += s1[0] * wv.x + s1[1] * wv.y + s1[2] * wv.z + s1[3] * wv.w;
    }
    out[(n0 + 2 * g) * 384 + j]     = acc0;
    out[(n0 + 2 * g + 1) * 384 + j] = acc1;
}

extern "C" void kernel_launch(void* const* d_in, const int* in_sizes, int n_in,
                              void* d_out, int out_size, void* d_ws, size_t ws_size,
                              hipStream_t stream)
{
    const float* s     = (const float*)d_in[0];
    const float* z     = (const float*)d_in[1];
    const float* rot   = (const float*)d_in[2];
    const float* trans = (const float*)d_in[3];
    const float* mask  = (const float*)d_in[4];
    const float* w_q   = (const float*)d_in[5];
    const float* b_q   = (const float*)d_in[6];
    const float* w_kv  = (const float*)d_in[7];
    const float* b_kv  = (const float*)d_in[8];
    const float* w_qp  = (const float*)d_in[9];
    const float* b_qp  = (const float*)d_in[10];
    const float* w_kvp = (const float*)d_in[11];
    const float* b_kvp = (const float*)d_in[12];
    const float* w_b   = (const float*)d_in[13];
    const float* b_b   = (const float*)d_in[14];
    const float* hwts  = (const float*)d_in[15];
    const float* w_out = (const float*)d_in[16];
    const float* b_out = (const float*)d_in[17];

    float* ws    = (float*)d_ws;
    float* q     = ws;                    // 768*192      =   147456
    float* kT    = q     + 147456;        // 192*768      =   147456 (transposed)
    float* qp    = kT    + 147456;        // 768*144      =   110592
    float* kpT   = qp    + 110592;        // 144*768      =   110592 (transposed)
    float* vcat  = kpT   + 110592;        // 768*480      =   368640 (row-major)
    float* zbT   = vcat  + 368640;        // 768*12*768   =  7077888 (transposed)
    float* ocat  = zbT   + 7077888;       // 768*2112     =  1622016
    // total: 9,584,640 floats = 38.3 MB

    k_proj<<<N_ / 2, 256, 0, stream>>>(s, rot, trans, w_q, b_q, w_kv, b_kv,
                                       w_qp, b_qp, w_kvp, b_kvp, q, kT, qp, kpT, vcat);
    k_zb<<<N_ * 12, 256, 0, stream>>>(z, w_b, b_b, zbT);
    k_fused<<<N_, 256, 0, stream>>>(q, kT, qp, kpT, vcat, zbT, z,
                                    hwts, mask, rot, trans, ocat);
    k_final<<<N_ / 2, 384, 0, stream>>>(ocat, w_out, b_out, (float*)d_out);
}

// Round 4
// 699.275 us; speedup vs baseline: 1.6778x; 1.2749x over previous
//
#include <hip/hip_runtime.h>

#define N_ 768
#define CS 384
#define CZ 128
#define HH 12
#define PQ_ 4
#define PV_ 8

// ---------------------------------------------------------------------------
// K0: zbT[n][h][m] = sqrt(1/3) * (z[n,m,:] @ w_b[h,:] + b_b[h])
// ---------------------------------------------------------------------------
__global__ __launch_bounds__(256, 4) void k_zb(
    const float* __restrict__ z,
    const float* __restrict__ w_b, const float* __restrict__ b_b,
    float* __restrict__ zbT)
{
    const int bid = blockIdx.x;
    const int n  = bid / 12;
    const int m0 = (bid % 12) * 64;
    const int tid = threadIdx.x;

    __shared__ float zs[64 * 133];
    __shared__ float zbt[64 * 13];

    const float4* zsrc = (const float4*)(z + ((size_t)n * N_ + m0) * CZ);
    #pragma unroll
    for (int j = 0; j < 8; ++j) {
        int idx = tid + j * 256;
        float4 zv = zsrc[idx];
        int f  = idx << 2;
        int ml = f >> 7;
        int c  = f & 127;
        float* d = &zs[ml * 133 + c];
        d[0] = zv.x; d[1] = zv.y; d[2] = zv.z; d[3] = zv.w;
    }
    __syncthreads();

    const int ml = tid & 63;
    const int hq = __builtin_amdgcn_readfirstlane(tid >> 6);
    const float* w0 = w_b + (hq * 3 + 0) * CZ;
    const float* w1 = w0 + CZ;
    const float* w2 = w1 + CZ;
    const float* zrow = &zs[ml * 133];
    float a0 = 0.f, a1 = 0.f, a2 = 0.f;
    #pragma unroll 8
    for (int c = 0; c < CZ; ++c) {
        float zv = zrow[c];
        a0 += zv * w0[c];
        a1 += zv * w1[c];
        a2 += zv * w2[c];
    }
    const float s3 = 0.5773502691896258f;
    zbt[ml * 13 + hq * 3 + 0] = s3 * (a0 + b_b[hq * 3 + 0]);
    zbt[ml * 13 + hq * 3 + 1] = s3 * (a1 + b_b[hq * 3 + 1]);
    zbt[ml * 13 + hq * 3 + 2] = s3 * (a2 + b_b[hq * 3 + 2]);
    __syncthreads();

    for (int idx = tid; idx < 768; idx += 256) {
        int h = idx >> 6, mm = idx & 63;
        zbT[(size_t)n * (HH * N_) + h * N_ + m0 + mm] = zbt[mm * 13 + h];
    }
}

// ---------------------------------------------------------------------------
// K1 (GEMM form): all projections as one GEMM OUT[1152 vrows][768 n] with a
// row PERMUTATION so each point's x,y,z are adjacent virtual rows:
//   rv <192          : q row rv
//   rv 192..575      : kv row rv-192 (h*32+c; c<16 -> k, else v)
//   rv 576..719      : rv-576 = hp*3+coord -> w_qp physical row coord*48+hp
//   rv 720..1151     : rv-720 = j*3+coord  -> w_kvp physical row coord*144+j
// Tile 24r x 64n, K=384 in 6 steps of 64. Grid 48*12=576.
// Epilogue applies bias (+rot/trans for point rows) and writes final layouts:
// q[n][192], kT[192][768], qp[n][144], kpT[144][768], vcat[n][480].
// ---------------------------------------------------------------------------
__global__ __launch_bounds__(256, 4) void k_proj(
    const float* __restrict__ s,
    const float* __restrict__ rot,
    const float* __restrict__ trans,
    const float* __restrict__ w_q,  const float* __restrict__ b_q,
    const float* __restrict__ w_kv, const float* __restrict__ b_kv,
    const float* __restrict__ w_qp, const float* __restrict__ b_qp,
    const float* __restrict__ w_kvp,const float* __restrict__ b_kvp,
    float* __restrict__ q, float* __restrict__ kT,
    float* __restrict__ qp, float* __restrict__ kpT,
    float* __restrict__ vcat)
{
    const int rt = blockIdx.x % 48;       // r-tile: virtual rows rt*24..+23
    const int nt = blockIdx.x / 48;       // n-tile: n nt*64..+63
    const int r0 = rt * 24;
    const int n0 = nt * 64;
    const int tid = threadIdx.x;

    __shared__ float Ws[64][36];          // [k][ (rl/3)*4 + rl%3 ]
    __shared__ float Ss[64][66];          // [k][n_local]
    __shared__ float Rsh[64][9], Tsh[64][3];
    __shared__ float bsh[24];

    // virtual-row -> (weight row ptr, bias)
    auto vmap = [&](int rv, const float*& wrow, float& bias) {
        if (rv < 192)      { wrow = w_q + (size_t)rv * CS;  bias = b_q[rv]; }
        else if (rv < 576) { int r = rv - 192; wrow = w_kv + (size_t)r * CS; bias = b_kv[r]; }
        else if (rv < 720) { int t = rv - 576; int hp = t / 3, d = t % 3;
                             int r = d * 48 + hp;  wrow = w_qp + (size_t)r * CS;  bias = b_qp[r]; }
        else               { int t = rv - 720; int j = t / 3, d = t % 3;
                             int r = d * 144 + j; wrow = w_kvp + (size_t)r * CS; bias = b_kvp[r]; }
    };

    if (tid < 24) {
        const float* wr; float bb;
        vmap(r0 + tid, wr, bb);
        bsh[tid] = bb;
    }
    if (r0 >= 576) {   // block-uniform: point tiles need rot/trans
        for (int idx = tid; idx < 64 * 9; idx += 256)
            Rsh[idx / 9][idx % 9] = rot[(size_t)(n0 + idx / 9) * 9 + idx % 9];
        for (int idx = tid; idx < 64 * 3; idx += 256)
            Tsh[idx / 3][idx % 3] = trans[(size_t)(n0 + idx / 3) * 3 + idx % 3];
    }

    const int g_n = tid & 31;             // n-group: n = n0 + g_n*2 + nn
    const int g_r = tid >> 5;             // 0..7: rows rv = r0 + g_r*3 + coord
    float acc[3][2] = {{0.f,0.f},{0.f,0.f},{0.f,0.f}};

    for (int ks = 0; ks < 6; ++ks) {
        const int kb = ks * 64;
        // stage W tile (24 rows x 64 k), transposed with coord-in-slot layout
        for (int t4 = tid; t4 < 384; t4 += 256) {
            int rl = t4 >> 4, c4 = t4 & 15;
            const float* wrow; float bb;
            vmap(r0 + rl, wrow, bb);
            float4 wv = *(const float4*)(wrow + kb + c4 * 4);
            int slot = (rl / 3) * 4 + rl % 3;
            Ws[c4 * 4 + 0][slot] = wv.x;
            Ws[c4 * 4 + 1][slot] = wv.y;
            Ws[c4 * 4 + 2][slot] = wv.z;
            Ws[c4 * 4 + 3][slot] = wv.w;
        }
        // stage S^T tile (64 k x 64 n)
        for (int t4 = tid; t4 < 1024; t4 += 256) {
            int nl = t4 >> 4, c4 = t4 & 15;
            float4 sv = *(const float4*)(s + (size_t)(n0 + nl) * CS + kb + c4 * 4);
            Ss[c4 * 4 + 0][nl] = sv.x;
            Ss[c4 * 4 + 1][nl] = sv.y;
            Ss[c4 * 4 + 2][nl] = sv.z;
            Ss[c4 * 4 + 3][nl] = sv.w;
        }
        __syncthreads();
        #pragma unroll 8
        for (int k = 0; k < 64; ++k) {
            float4 w  = *(const float4*)&Ws[k][g_r * 4];
            float2 sv = *(const float2*)&Ss[k][g_n * 2];
            acc[0][0] += w.x * sv.x;  acc[0][1] += w.x * sv.y;
            acc[1][0] += w.y * sv.x;  acc[1][1] += w.y * sv.y;
            acc[2][0] += w.z * sv.x;  acc[2][1] += w.z * sv.y;
        }
        __syncthreads();
    }

    // ---- epilogue: bias + region-specific scatter ----
    const float b0 = bsh[g_r * 3 + 0];
    const float b1 = bsh[g_r * 3 + 1];
    const float b2 = bsh[g_r * 3 + 2];
    const int rvb = r0 + g_r * 3;

    if (rvb < 192) {
        #pragma unroll
        for (int nn = 0; nn < 2; ++nn) {
            int n = n0 + g_n * 2 + nn;
            q[(size_t)n * 192 + rvb + 0] = acc[0][nn] + b0;
            q[(size_t)n * 192 + rvb + 1] = acc[1][nn] + b1;
            q[(size_t)n * 192 + rvb + 2] = acc[2][nn] + b2;
        }
    } else if (rvb < 576) {
        #pragma unroll
        for (int cc = 0; cc < 3; ++cc) {
            int i = rvb + cc - 192;
            int h = i >> 5, c = i & 31;
            float bb = (cc == 0) ? b0 : (cc == 1) ? b1 : b2;
            if (c < 16) {
                float2 st = make_float2(acc[cc][0] + bb, acc[cc][1] + bb);
                *(float2*)&kT[(size_t)(h * 16 + c) * N_ + n0 + g_n * 2] = st;
            } else {
                vcat[(size_t)(n0 + g_n * 2 + 0) * 480 + h * 16 + c - 16] = acc[cc][0] + bb;
                vcat[(size_t)(n0 + g_n * 2 + 1) * 480 + h * 16 + c - 16] = acc[cc][1] + bb;
            }
        }
    } else if (rvb < 720) {
        int hp = (rvb - 576) / 3;
        #pragma unroll
        for (int nn = 0; nn < 2; ++nn) {
            int nl = g_n * 2 + nn, n = n0 + nl;
            float x = acc[0][nn] + b0, y = acc[1][nn] + b1, zc = acc[2][nn] + b2;
            const float* R = Rsh[nl];
            const float* T = Tsh[nl];
            #pragma unroll
            for (int d = 0; d < 3; ++d)
                qp[(size_t)n * 144 + hp * 3 + d] =
                    R[d * 3 + 0] * x + R[d * 3 + 1] * y + R[d * 3 + 2] * zc + T[d];
        }
    } else {
        int j = (rvb - 720) / 3;
        int h = j / 12, p = j % 12;
        float px[2][3];
        #pragma unroll
        for (int nn = 0; nn < 2; ++nn) {
            int nl = g_n * 2 + nn;
            float x = acc[0][nn] + b0, y = acc[1][nn] + b1, zc = acc[2][nn] + b2;
            const float* R = Rsh[nl];
            const float* T = Tsh[nl];
            #pragma unroll
            for (int d = 0; d < 3; ++d)
                px[nn][d] = R[d * 3 + 0] * x + R[d * 3 + 1] * y + R[d * 3 + 2] * zc + T[d];
        }
        if (p < PQ_) {
            #pragma unroll
            for (int d = 0; d < 3; ++d)
                *(float2*)&kpT[(size_t)(h * 12 + p * 3 + d) * N_ + n0 + g_n * 2] =
                    make_float2(px[0][d], px[1][d]);
        } else {
            int base = 192 + (h * PV_ + p - PQ_) * 3;
            #pragma unroll
            for (int nn = 0; nn < 2; ++nn) {
                int n = n0 + g_n * 2 + nn;
                #pragma unroll
                for (int d = 0; d < 3; ++d)
                    vcat[(size_t)n * 480 + base + d] = px[nn][d];
            }
        }
    }
}

// ---------------------------------------------------------------------------
// K2 (fused): unchanged from round 3.
// ---------------------------------------------------------------------------
__global__ __launch_bounds__(256, 4) void k_fused(
    const float* __restrict__ q, const float* __restrict__ kT,
    const float* __restrict__ qp, const float* __restrict__ kpT,
    const float* __restrict__ vcat,
    const float* __restrict__ zbT,
    const float* __restrict__ z,
    const float* __restrict__ head_weights,
    const float* __restrict__ mask,
    const float* __restrict__ rot, const float* __restrict__ trans,
    float* __restrict__ ocat)
{
    const int n   = (N_ - 1) - blockIdx.x;
    const int tid = threadIdx.x;

    __shared__ float qv[192], qpt[144];
    __shared__ float hw[HH];
    __shared__ float L[HH * N_];
    __shared__ float og[288];
    __shared__ float R[9], T[3];

    for (int i = tid; i < 192; i += 256) qv[i] = q[n * 192 + i];
    for (int i = tid; i < 144; i += 256) qpt[i] = qp[n * 144 + i];
    if (tid < HH) {
        float x = head_weights[tid];
        hw[tid] = 0.13608276348795434f * logf(1.0f + expf(x));
    }
    if (tid < 9) R[tid] = rot[n * 9 + tid];
    if (tid < 3) T[tid] = trans[n * 3 + tid];
    __syncthreads();

    const float mn = mask[n];

    if (tid < 192) {
        const int m0 = tid * 4;
        float4 mk = *(const float4*)(mask + m0);
        float mt0 = (mn * mk.x - 1.0f) * 100000.0f;
        float mt1 = (mn * mk.y - 1.0f) * 100000.0f;
        float mt2 = (mn * mk.z - 1.0f) * 100000.0f;
        float mt3 = (mn * mk.w - 1.0f) * 100000.0f;
        const float* zbn = zbT + (size_t)n * (HH * N_);
        #pragma unroll
        for (int h = 0; h < HH; ++h) {
            float ax = 0.f, ay = 0.f, az = 0.f, aw = 0.f;
            #pragma unroll
            for (int c = 0; c < 16; ++c) {
                float qc = qv[h * 16 + c];
                float4 kx = *(const float4*)&kT[(size_t)(h * 16 + c) * N_ + m0];
                ax += qc * kx.x; ay += qc * kx.y; az += qc * kx.z; aw += qc * kx.w;
            }
            const float s48 = 0.14433756729740643f;
            ax *= s48; ay *= s48; az *= s48; aw *= s48;
            float4 zb4 = *(const float4*)&zbn[h * N_ + m0];
            ax += zb4.x; ay += zb4.y; az += zb4.z; aw += zb4.w;
            float dx = 0.f, dy = 0.f, dz = 0.f, dw = 0.f;
            #pragma unroll
            for (int pd = 0; pd < 12; ++pd) {
                float qd = qpt[h * 12 + pd];
                float4 kd = *(const float4*)&kpT[(size_t)(h * 12 + pd) * N_ + m0];
                float ex = qd - kd.x, ey = qd - kd.y, ez = qd - kd.z, ew = qd - kd.w;
                dx += ex * ex; dy += ey * ey; dz += ez * ez; dw += ew * ew;
            }
            float hwh = 0.5f * hw[h];
            float4 out;
            out.x = ax - hwh * dx + mt0;
            out.y = ay - hwh * dy + mt1;
            out.z = az - hwh * dz + mt2;
            out.w = aw - hwh * dw + mt3;
            *(float4*)&L[h * N_ + m0] = out;
        }
    }
    __syncthreads();

    {
        const int wv_ = tid >> 6, lane = tid & 63;
        #pragma unroll
        for (int j = 0; j < 3; ++j) {
            const int h = wv_ + 4 * j;
            float vals[12];
            float mx = -1e30f;
            #pragma unroll
            for (int t = 0; t < 12; ++t) {
                vals[t] = L[h * N_ + lane + 64 * t];
                mx = fmaxf(mx, vals[t]);
            }
            #pragma unroll
            for (int off = 32; off; off >>= 1) mx = fmaxf(mx, __shfl_xor(mx, off));
            float sum = 0.f;
            #pragma unroll
            for (int t = 0; t < 12; ++t) { vals[t] = expf(vals[t] - mx); sum += vals[t]; }
            #pragma unroll
            for (int off = 32; off; off >>= 1) sum += __shfl_xor(sum, off);
            float inv = 1.0f / sum;
            #pragma unroll
            for (int t = 0; t < 12; ++t) L[h * N_ + lane + 64 * t] = vals[t] * inv;
        }
    }
    __syncthreads();

    float* oc = ocat + (size_t)n * 2112;

    {
        const int i0 = tid;
        const int i1 = tid + 256;
        const bool act1 = (i1 < 480);
        const int h0 = (i0 < 192) ? (i0 >> 4) : ((i0 - 192) / 24);
        const int h1 = act1 ? ((i1 - 192) / 24) : 0;
        const float* Lh0 = L + h0 * N_;
        const float* Lh1 = L + h1 * N_;
        const float* vc0 = vcat + i0;
        const float* vc1 = vcat + (act1 ? i1 : 0);
        float a0 = 0.f, a1 = 0.f;
        #pragma unroll 8
        for (int m = 0; m < N_; ++m) {
            float x0 = vc0[(size_t)m * 480];
            float x1 = vc1[(size_t)m * 480];
            a0 += Lh0[m] * x0;
            a1 += Lh1[m] * x1;
        }
        if (i0 < 192) oc[i0] = a0; else og[i0 - 192] = a0;
        if (act1) og[i1 - 192] = a1;
    }

    {
        const int c4 = tid & 31;
        const int g  = tid >> 5;
        const float4* zr = (const float4*)(z + (size_t)n * N_ * CZ) + c4;
        float4 acc[HH];
        #pragma unroll
        for (int h = 0; h < HH; ++h) { acc[h].x = acc[h].y = acc[h].z = acc[h].w = 0.f; }
        const int ms = g * 96;
        #pragma unroll 4
        for (int m = ms; m < ms + 96; ++m) {
            float4 zz = zr[(size_t)m * 32];
            #pragma unroll
            for (int h = 0; h < HH; ++h) {
                float lh = L[h * N_ + m];
                acc[h].x += lh * zz.x; acc[h].y += lh * zz.y;
                acc[h].z += lh * zz.z; acc[h].w += lh * zz.w;
            }
        }
        #pragma unroll
        for (int h = 0; h < HH; ++h) {
            acc[h].x += __shfl_xor(acc[h].x, 32);
            acc[h].y += __shfl_xor(acc[h].y, 32);
            acc[h].z += __shfl_xor(acc[h].z, 32);
            acc[h].w += __shfl_xor(acc[h].w, 32);
        }
        __syncthreads();
        float4* part4 = (float4*)L;
        if ((tid & 63) < 32) {
            const int w = tid >> 6;
            #pragma unroll
            for (int h = 0; h < HH; ++h)
                part4[(w * HH + h) * 32 + c4] = acc[h];
        }
        __syncthreads();
        const float* part = (const float*)L;
        for (int idx = tid; idx < HH * CZ; idx += 256) {
            float sum = part[idx] + part[1536 + idx] + part[3072 + idx] + part[4608 + idx];
            oc[576 + idx] = sum;
        }
    }

    for (int hp = tid; hp < 96; hp += 256) {
        float gx = og[hp * 3 + 0] - T[0];
        float gy = og[hp * 3 + 1] - T[1];
        float gz = og[hp * 3 + 2] - T[2];
        float lx = R[0] * gx + R[3] * gy + R[6] * gz;
        float ly = R[1] * gx + R[4] * gy + R[7] * gz;
        float lz = R[2] * gx + R[5] * gy + R[8] * gz;
        oc[192 + hp] = lx;
        oc[288 + hp] = ly;
        oc[384 + hp] = lz;
        oc[480 + hp] = sqrtf(lx * lx + ly * ly + lz * lz + 1e-8f);
    }
}

// ---------------------------------------------------------------------------
// K3a: out init with bias (atomic targets must be pre-initialized).
// ---------------------------------------------------------------------------
__global__ __launch_bounds__(384) void k_init(
    const float* __restrict__ b_out, float* __restrict__ out)
{
    out[(size_t)blockIdx.x * 384 + threadIdx.x] = b_out[threadIdx.x];
}

// ---------------------------------------------------------------------------
// K3b: out[n][j] += o_cat[n,:k-quarter] . w_out[j,:k-quarter]
// LDS-tiled GEMM, tile 16n x 64j x 528k. Grid 48*6*4 = 1152.
// w_out staged coalesced into LDS (stride 49: conflict-free compute reads);
// ocat staged transposed (As_t[k][n]) so compute reads are wave-broadcast.
// ---------------------------------------------------------------------------
__global__ __launch_bounds__(256, 6) void k_final(
    const float* __restrict__ ocat,
    const float* __restrict__ w_out,
    float* __restrict__ out)
{
    const int b  = blockIdx.x;
    const int bk = b & 3;                 // k-quarter
    const int bn = (b >> 2) % 48;         // n-tile (16)
    const int bj = (b >> 2) / 48;         // j-tile (64)
    const int n0 = bn * 16, j0 = bj * 64, kq0 = bk * 528;
    const int tid = threadIdx.x;

    __shared__ float As_t[48][20];        // [k][n_local]
    __shared__ float Bs[64][49];          // [j_local][k]

    const int tj = tid & 63;
    const int tn = tid >> 6;              // wave id: n-group of 4 (wave-uniform)
    float a0 = 0.f, a1 = 0.f, a2 = 0.f, a3 = 0.f;

    for (int st = 0; st < 11; ++st) {
        const int kb = kq0 + st * 48;
        // stage As_t: 16 n x 48 k, transposed
        for (int t4 = tid; t4 < 192; t4 += 256) {
            int nl = t4 / 12, c4 = t4 % 12;
            float4 av = *(const float4*)(ocat + (size_t)(n0 + nl) * 2112 + kb + c4 * 4);
            As_t[c4 * 4 + 0][nl] = av.x;
            As_t[c4 * 4 + 1][nl] = av.y;
            As_t[c4 * 4 + 2][nl] = av.z;
            As_t[c4 * 4 + 3][nl] = av.w;
        }
        // stage Bs: 64 j x 48 k
        for (int t4 = tid; t4 < 768; t4 += 256) {
            int jr = t4 / 12, c4 = t4 % 12;
            float4 wv = *(const float4*)(w_out + (size_t)(j0 + jr) * 2112 + kb + c4 * 4);
            Bs[jr][c4 * 4 + 0] = wv.x;
            Bs[jr][c4 * 4 + 1] = wv.y;
            Bs[jr][c4 * 4 + 2] = wv.z;
            Bs[jr][c4 * 4 + 3] = wv.w;
        }
        __syncthreads();
        #pragma unroll 8
        for (int k = 0; k < 48; ++k) {
            float bb = Bs[tj][k];
            float4 av = *(const float4*)&As_t[k][tn * 4];   // wave-broadcast
            a0 += bb * av.x; a1 += bb * av.y; a2 += bb * av.z; a3 += bb * av.w;
        }
        __syncthreads();
    }

    float* op = out + (size_t)(n0 + tn * 4) * 384 + j0 + tj;
    atomicAdd(op + 0 * 384, a0);
    atomicAdd(op + 1 * 384, a1);
    atomicAdd(op + 2 * 384, a2);
    atomicAdd(op + 3 * 384, a3);
}

extern "C" void kernel_launch(void* const* d_in, const int* in_sizes, int n_in,
                              void* d_out, int out_size, void* d_ws, size_t ws_size,
                              hipStream_t stream)
{
    const float* s     = (const float*)d_in[0];
    const float* z     = (const float*)d_in[1];
    const float* rot   = (const float*)d_in[2];
    const float* trans = (const float*)d_in[3];
    const float* mask  = (const float*)d_in[4];
    const float* w_q   = (const float*)d_in[5];
    const float* b_q   = (const float*)d_in[6];
    const float* w_kv  = (const float*)d_in[7];
    const float* b_kv  = (const float*)d_in[8];
    const float* w_qp  = (const float*)d_in[9];
    const float* b_qp  = (const float*)d_in[10];
    const float* w_kvp = (const float*)d_in[11];
    const float* b_kvp = (const float*)d_in[12];
    const float* w_b   = (const float*)d_in[13];
    const float* b_b   = (const float*)d_in[14];
    const float* hwts  = (const float*)d_in[15];
    const float* w_out = (const float*)d_in[16];
    const float* b_out = (const float*)d_in[17];

    float* ws    = (float*)d_ws;
    float* q     = ws;                    // 768*192      =   147456
    float* kT    = q     + 147456;        // 192*768      =   147456 (transposed)
    float* qp    = kT    + 147456;        // 768*144      =   110592
    float* kpT   = qp    + 110592;        // 144*768      =   110592 (transposed)
    float* vcat  = kpT   + 110592;        // 768*480      =   368640 (row-major)
    float* zbT   = vcat  + 368640;        // 768*12*768   =  7077888 (transposed)
    float* ocat  = zbT   + 7077888;       // 768*2112     =  1622016
    // total: 9,584,640 floats = 38.3 MB

    k_init<<<N_, 384, 0, stream>>>(b_out, (float*)d_out);
    k_proj<<<576, 256, 0, stream>>>(s, rot, trans, w_q, b_q, w_kv, b_kv,
                                    w_qp, b_qp, w_kvp, b_kvp, q, kT, qp, kpT, vcat);
    k_zb<<<N_ * 12, 256, 0, stream>>>(z, w_b, b_b, zbT);
    k_fused<<<N_, 256, 0, stream>>>(q, kT, qp, kpT, vcat, zbT, z,
                                    hwts, mask, rot, trans, ocat);
    k_final<<<1152, 256, 0, stream>>>(ocat, w_out, (float*)d_out);
}